// Round 2
// baseline (990.409 us; speedup 1.0000x reference)
//
#include <hip/hip_runtime.h>

#define TT 2048      // tokens (B*S)
#define HD 2048      // hidden
#define FD 1408      // per-expert ffn
#define SFD 5632     // shared ffn
#define NE 8         // experts
#define BM 128
#define BN 128
#define BK 32

using f32x4 = __attribute__((ext_vector_type(4))) float;
using s16x8 = __attribute__((ext_vector_type(8))) short;

__device__ __forceinline__ unsigned short f2bf(float f) {
    union { float f; unsigned u; } v; v.f = f;
    unsigned r = v.u + 0x7fff + ((v.u >> 16) & 1);   // RNE
    return (unsigned short)(r >> 16);
}
__device__ __forceinline__ float bf2f(unsigned short u) {
    union { unsigned u; float f; } v; v.u = ((unsigned)u) << 16;
    return v.f;
}

__device__ __forceinline__ void gload16(const void* g, void* l) {
    __builtin_amdgcn_global_load_lds(
        (const __attribute__((address_space(1))) unsigned*)g,
        (__attribute__((address_space(3))) unsigned*)l, 16, 0, 0);
}

// ---- fp32 -> bf16 activation conversion -------------------------------------
__global__ void cvt_kernel(const float* __restrict__ x, unsigned short* __restrict__ xb) {
    size_t i = ((size_t)blockIdx.x * 256 + threadIdx.x) * 8;
    float4 f0 = *(const float4*)(x + i);
    float4 f1 = *(const float4*)(x + i + 4);
    s16x8 v;
    v[0]=(short)f2bf(f0.x); v[1]=(short)f2bf(f0.y); v[2]=(short)f2bf(f0.z); v[3]=(short)f2bf(f0.w);
    v[4]=(short)f2bf(f1.x); v[5]=(short)f2bf(f1.y); v[6]=(short)f2bf(f1.z); v[7]=(short)f2bf(f1.w);
    *(s16x8*)(xb + i) = v;
}

// ---- router: fp32 softmax, top-2, expert lists, shared sigmoid gate ---------
__global__ void router_kernel(const float* __restrict__ x, const float* __restrict__ gw,
                              const float* __restrict__ segw,
                              int* counts, int* tlist, float* wlist, float* gateval,
                              int* selpos) {
    int wave = threadIdx.x >> 6;
    int lane = threadIdx.x & 63;
    int t = blockIdx.x * 4 + wave;
    float acc[9];
    #pragma unroll
    for (int i = 0; i < 9; ++i) acc[i] = 0.f;
    const float* xrow = x + (size_t)t * HD;
    for (int h = lane; h < HD; h += 64) {
        float xv = xrow[h];
        #pragma unroll
        for (int e = 0; e < NE; ++e) acc[e] += xv * gw[e * HD + h];
        acc[8] += xv * segw[h];
    }
    #pragma unroll
    for (int i = 0; i < 9; ++i) {
        float v = acc[i];
        #pragma unroll
        for (int s = 32; s > 0; s >>= 1) v += __shfl_xor(v, s);
        acc[i] = v;
    }
    if (lane == 0) {
        float m = acc[0];
        #pragma unroll
        for (int e = 1; e < NE; ++e) m = fmaxf(m, acc[e]);
        float p[NE], sum = 0.f;
        #pragma unroll
        for (int e = 0; e < NE; ++e) { p[e] = expf(acc[e] - m); sum += p[e]; }
        float inv = 1.f / sum;
        int b1 = 0, b2 = -1; float v1 = p[0], v2 = -1.f;
        #pragma unroll
        for (int e = 1; e < NE; ++e) {
            if (p[e] > v1) { v2 = v1; b2 = b1; v1 = p[e]; b1 = e; }
            else if (p[e] > v2) { v2 = p[e]; b2 = e; }
        }
        v1 *= inv; v2 *= inv;
        int s1 = atomicAdd(&counts[b1], 1); tlist[b1 * TT + s1] = t; wlist[b1 * TT + s1] = v1;
        int s2 = atomicAdd(&counts[b2], 1); tlist[b2 * TT + s2] = t; wlist[b2 * TT + s2] = v2;
        selpos[2 * t]     = b1 * TT + s1;
        selpos[2 * t + 1] = b2 * TT + s2;
        gateval[t] = 1.f / (1.f + expf(-acc[8]));
    }
}

__global__ void prefix_kernel(const int* counts, int* offsets) {
    if (threadIdx.x == 0) {
        int s = 0;
        for (int e = 0; e < NE; ++e) { offsets[e] = s; s += counts[e]; }
    }
}

// ---- combine: out[t] += w0*robuf[row0] + w1*robuf[row1] ---------------------
__global__ void combine_kernel(const int* __restrict__ selpos, const float* __restrict__ wlist,
                               const int* __restrict__ offsets,
                               const unsigned short* __restrict__ robuf, float* __restrict__ out) {
    int t = blockIdx.x;
    int p0 = selpos[2 * t], p1 = selpos[2 * t + 1];
    float w0 = wlist[p0], w1 = wlist[p1];
    int r0 = offsets[p0 >> 11] + (p0 & (TT - 1));   // TT = 2048 = 1<<11
    int r1 = offsets[p1 >> 11] + (p1 & (TT - 1));
    int c = threadIdx.x * 8;
    s16x8 a = *(const s16x8*)(robuf + (size_t)r0 * HD + c);
    s16x8 b = *(const s16x8*)(robuf + (size_t)r1 * HD + c);
    float* op = out + (size_t)t * HD + c;
    float4 o0 = *(float4*)op, o1 = *(float4*)(op + 4);
    o0.x += w0 * bf2f((unsigned short)a[0]) + w1 * bf2f((unsigned short)b[0]);
    o0.y += w0 * bf2f((unsigned short)a[1]) + w1 * bf2f((unsigned short)b[1]);
    o0.z += w0 * bf2f((unsigned short)a[2]) + w1 * bf2f((unsigned short)b[2]);
    o0.w += w0 * bf2f((unsigned short)a[3]) + w1 * bf2f((unsigned short)b[3]);
    o1.x += w0 * bf2f((unsigned short)a[4]) + w1 * bf2f((unsigned short)b[4]);
    o1.y += w0 * bf2f((unsigned short)a[5]) + w1 * bf2f((unsigned short)b[5]);
    o1.z += w0 * bf2f((unsigned short)a[6]) + w1 * bf2f((unsigned short)b[6]);
    o1.w += w0 * bf2f((unsigned short)a[7]) + w1 * bf2f((unsigned short)b[7]);
    *(float4*)op = o0; *(float4*)(op + 4) = o1;
}

// ---- pipelined GEMM: C[M,N(,x2)] = A[M,K](bf16) @ B[N,K](fp32->bf16)^T ------
// double-buffered LDS; A via global_load_lds (per-lane gathered src, linear dest);
// B reg-staged fp32->bf16, ds_write after MFMA (latency hidden under compute).
// EPI 0: C = bf16(silu(g)*u), fused gate+up (NB=2)
// EPI 1: C = bf16(acc)                      (routed down -> robuf)
// EPI 2: atomicAdd out[tok] += w*acc        (fallback if ws too small)
// EPI 3: out[row] = gateval[row]*acc        (shared down)
template<int NB, int EPI, bool GATHER>
__global__ __launch_bounds__(256)
void gemm2(const unsigned short* __restrict__ A, int lda,
           const float* __restrict__ B0, const float* __restrict__ B1,
           size_t eStrideB, int ldb, int K, int Mfixed,
           const int* __restrict__ counts, const int* __restrict__ offsets,
           const int* __restrict__ tlist, const float* __restrict__ wlist,
           unsigned short* __restrict__ C, int ldc,
           const float* __restrict__ gateval, float* __restrict__ out, int ldout) {
    __shared__ s16x8 As[2][512];
    __shared__ s16x8 Bs[NB][2][512];

    int e = blockIdx.z;
    int M = counts ? counts[e] : Mfixed;
    int m0 = blockIdx.y * BM;
    if (M == 0 || m0 >= M) return;
    int n0 = blockIdx.x * BN;
    int row_off = offsets ? offsets[e] : 0;
    const float* Bp0 = B0 + (size_t)e * eStrideB;
    const float* Bp1 = (NB == 2) ? B1 + (size_t)e * eStrideB : B0;

    int tid = threadIdx.x;
    int lane = tid & 63, w = tid >> 6;

    // A staging pointers: lane covers row it*64+lane, wave w covers k-group w
    const unsigned short* aptr[2];
    #pragma unroll
    for (int it = 0; it < 2; ++it) {
        int ar = m0 + it * 64 + lane; if (ar > M - 1) ar = M - 1;
        size_t grow;
        if constexpr (GATHER) grow = (size_t)tlist[e * TT + ar];
        else                  grow = (size_t)(row_off + ar);
        aptr[it] = A + grow * (size_t)lda;
    }
    // B staging pointers: thread pair covers one row's 32 k-floats
    int srow = tid >> 1, kg0 = (tid & 1) * 2;
    const float* bptr0 = Bp0 + (size_t)(n0 + srow) * ldb + kg0 * 8;
    const float* bptr1 = Bp1 + (size_t)(n0 + srow) * ldb + kg0 * 8;

    int wm = (w >> 1) * 64, wn = (w & 1) * 64;
    int grp = lane >> 4, l16 = lane & 15;

    f32x4 acc[NB][4][4];
    f32x4 zero = {0.f, 0.f, 0.f, 0.f};
    #pragma unroll
    for (int m = 0; m < NB; ++m)
        #pragma unroll
        for (int mi = 0; mi < 4; ++mi)
            #pragma unroll
            for (int ni = 0; ni < 4; ++ni) acc[m][mi][ni] = zero;

    float4 breg[NB][4];

    auto stageA = [&](int buf, int k0) {
        #pragma unroll
        for (int it = 0; it < 2; ++it)
            gload16(aptr[it] + k0 + w * 8, (void*)&As[buf][w * 128 + it * 64]);
    };
    auto loadB = [&](int k0) {
        #pragma unroll
        for (int j = 0; j < 2; ++j) {
            breg[0][j * 2]     = *(const float4*)(bptr0 + k0 + j * 8);
            breg[0][j * 2 + 1] = *(const float4*)(bptr0 + k0 + j * 8 + 4);
            if constexpr (NB == 2) {
                breg[1][j * 2]     = *(const float4*)(bptr1 + k0 + j * 8);
                breg[1][j * 2 + 1] = *(const float4*)(bptr1 + k0 + j * 8 + 4);
            }
        }
    };
    auto writeB = [&](int buf) {
        #pragma unroll
        for (int m = 0; m < NB; ++m)
            #pragma unroll
            for (int j = 0; j < 2; ++j) {
                float4 f0 = breg[m][j * 2], f1 = breg[m][j * 2 + 1];
                s16x8 v;
                v[0]=(short)f2bf(f0.x); v[1]=(short)f2bf(f0.y); v[2]=(short)f2bf(f0.z); v[3]=(short)f2bf(f0.w);
                v[4]=(short)f2bf(f1.x); v[5]=(short)f2bf(f1.y); v[6]=(short)f2bf(f1.z); v[7]=(short)f2bf(f1.w);
                Bs[m][buf][(kg0 + j) * 128 + srow] = v;
            }
    };

    stageA(0, 0); loadB(0); writeB(0);
    __syncthreads();

    int NT = K / BK;
    for (int kt = 0; kt < NT; ++kt) {
        int cur = kt & 1;
        bool more = (kt + 1 < NT);
        if (more) { stageA(cur ^ 1, (kt + 1) * BK); loadB((kt + 1) * BK); }
        s16x8 af[4];
        #pragma unroll
        for (int i = 0; i < 4; ++i) af[i] = As[cur][grp * 128 + wm + i * 16 + l16];
        #pragma unroll
        for (int ni = 0; ni < 4; ++ni) {
            #pragma unroll
            for (int m = 0; m < NB; ++m) {
                s16x8 bf = Bs[m][cur][grp * 128 + wn + ni * 16 + l16];
                #pragma unroll
                for (int mi = 0; mi < 4; ++mi)
                    acc[m][mi][ni] = __builtin_amdgcn_mfma_f32_16x16x32_bf16(af[mi], bf, acc[m][mi][ni], 0, 0, 0);
            }
        }
        if (more) writeB(cur ^ 1);
        __syncthreads();
    }

    // epilogue: frag row = (lane>>4)*4 + r, col = lane&15
    #pragma unroll
    for (int mi = 0; mi < 4; ++mi) {
        #pragma unroll
        for (int r = 0; r < 4; ++r) {
            int mrow = m0 + wm + mi * 16 + (lane >> 4) * 4 + r;
            if (mrow >= M) continue;
            #pragma unroll
            for (int ni = 0; ni < 4; ++ni) {
                int col = n0 + wn + ni * 16 + l16;
                if constexpr (EPI == 0) {
                    float g = acc[0][mi][ni][r], u = acc[1][mi][ni][r];
                    C[(size_t)(row_off + mrow) * ldc + col] = f2bf(g * u / (1.f + __expf(-g)));
                } else if constexpr (EPI == 1) {
                    C[(size_t)(row_off + mrow) * ldc + col] = f2bf(acc[0][mi][ni][r]);
                } else if constexpr (EPI == 2) {
                    int tok = tlist[e * TT + mrow]; float wv = wlist[e * TT + mrow];
                    atomicAdd(out + (size_t)tok * ldout + col, wv * acc[0][mi][ni][r]);
                } else {
                    out[(size_t)mrow * ldout + col] = gateval[mrow] * acc[0][mi][ni][r];
                }
            }
        }
    }
}

extern "C" void kernel_launch(void* const* d_in, const int* in_sizes, int n_in,
                              void* d_out, int out_size, void* d_ws, size_t ws_size,
                              hipStream_t stream) {
    const float* x    = (const float*)d_in[0];
    const float* gw   = (const float*)d_in[1];
    const float* gpw  = (const float*)d_in[2];
    const float* upw  = (const float*)d_in[3];
    const float* dpw  = (const float*)d_in[4];
    const float* sgw  = (const float*)d_in[5];
    const float* suw  = (const float*)d_in[6];
    const float* sdw  = (const float*)d_in[7];
    const float* segw = (const float*)d_in[8];
    float* out = (float*)d_out;
    char* ws = (char*)d_ws;

    int*   counts  = (int*)(ws + 0);
    int*   offsets = (int*)(ws + 64);
    int*   tlist   = (int*)(ws + 256);        // 64 KB
    float* wlist   = (float*)(ws + 65792);    // 64 KB
    float* gateval = (float*)(ws + 131328);   // 8 KB
    int*   selpos  = (int*)(ws + 139520);     // 16 KB
    unsigned short* xb    = (unsigned short*)(ws + 155904);     // 8 MB bf16 activations
    unsigned short* gbuf  = (unsigned short*)(ws + 8544512);    // 23.1 MB (shared) / 11.5 MB (routed)
    unsigned short* robuf = (unsigned short*)(ws + 20078848);   // 16.8 MB, after routed gbuf
    size_t needed = 20078848 + (size_t)4096 * HD * 2;           // ~36.9 MB

    hipMemsetAsync(counts, 0, 64, stream);
    cvt_kernel<<<dim3(TT * HD / (256 * 8)), 256, 0, stream>>>(x, xb);
    router_kernel<<<dim3(TT / 4), 256, 0, stream>>>(x, gw, segw, counts, tlist, wlist, gateval, selpos);
    prefix_kernel<<<dim3(1), 64, 0, stream>>>(counts, offsets);

    // shared expert: fused gate+up -> gbuf, then gated down -> out (writes all of out)
    gemm2<2, 0, false><<<dim3(SFD / BN, TT / BM, 1), 256, 0, stream>>>(
        xb, HD, sgw, suw, 0, HD, HD, TT, nullptr, nullptr, nullptr, nullptr, gbuf, SFD, nullptr, nullptr, 0);
    gemm2<1, 3, false><<<dim3(HD / BN, TT / BM, 1), 256, 0, stream>>>(
        gbuf, SFD, sdw, nullptr, 0, SFD, SFD, TT, nullptr, nullptr, nullptr, nullptr, nullptr, 0, gateval, out, HD);

    // routed experts: fused gate+up -> gbuf (expert-sorted rows)
    gemm2<2, 0, true><<<dim3(FD / BN, TT / BM, NE), 256, 0, stream>>>(
        xb, HD, gpw, upw, (size_t)FD * HD, HD, HD, 0, counts, offsets, tlist, nullptr, gbuf, FD, nullptr, nullptr, 0);

    if (ws_size >= needed) {
        // down -> robuf (no atomics), then per-token combine
        gemm2<1, 1, false><<<dim3(HD / BN, TT / BM, NE), 256, 0, stream>>>(
            gbuf, FD, dpw, nullptr, (size_t)HD * FD, FD, FD, 0, counts, offsets, nullptr, nullptr, robuf, HD, nullptr, nullptr, 0);
        combine_kernel<<<dim3(TT), 256, 0, stream>>>(selpos, wlist, offsets, robuf, out);
    } else {
        // fallback: atomic scatter-add (round-1 behavior)
        gemm2<1, 2, false><<<dim3(HD / BN, TT / BM, NE), 256, 0, stream>>>(
            gbuf, FD, dpw, nullptr, (size_t)HD * FD, FD, FD, 0, counts, offsets, tlist, wlist, nullptr, 0, nullptr, out, HD);
    }
}